// Round 8
// baseline (2793.780 us; speedup 1.0000x reference)
//
#include <hip/hip_runtime.h>
#include <hip/hip_bf16.h>
#include <cstdint>

#define NDIRS 16384
#define DMODEL 1024
#define BATCH 4096
#define KTOP 32
#define MKK 128
#define AUXK 256
#define DEADTHR 266
#define CAND_MAX 2048
// BLIS/AOCL-Zen sgemm K-blocking: KC=512, no tail balancing ->
// panels [0,512) [512,1024) -> fold after 16-wide tile 31 (second panel folds
// in the epilogue).
#define FOLD_T0 31
#define FOLD_T1 (-1)

__device__ __forceinline__ unsigned fkey(float f) {
  unsigned u = __float_as_uint(f);
  return (u & 0x80000000u) ? ~u : (u | 0x80000000u);
}

// ---------------- W_dec [DMODEL][NDIRS] -> WdT [NDIRS][DMODEL] ----------------
__global__ __launch_bounds__(256) void k_transpose(const float* __restrict__ Wdec,
                                                   float* __restrict__ WdT) {
  __shared__ float tile[32][33];
  const int tx = threadIdx.x & 31, ty = threadIdx.x >> 5;
  const int c0 = blockIdx.x * 32;
  const int r0 = blockIdx.y * 32;
#pragma unroll
  for (int i = 0; i < 32; i += 8)
    tile[ty + i][tx] = Wdec[(size_t)(r0 + ty + i) * NDIRS + c0 + tx];
  __syncthreads();
#pragma unroll
  for (int i = 0; i < 32; i += 8)
    WdT[(size_t)(c0 + ty + i) * DMODEL + r0 + tx] = tile[tx][ty + i];
}

// ---- P = fl32(x-pb) @ Wenc^T + lb, replicating BLIS/AOCL-Zen sgemm rounding:
// K panels {512,512} (KC=512, no tail balance); within a panel: sequential
// ascending-k FMA into one fp32 accumulator; panels combined in order by fp32
// adds (C=p0; C+=p1); then one fp32 +latent_bias.
// 128x128 tile, K-step 16, 256 threads, 8x8 micro-tile per thread.
__global__ __launch_bounds__(256, 2) void k_gemm_enc(
    const float* __restrict__ x, const float* __restrict__ Wenc,
    const float* __restrict__ pre_bias, const float* __restrict__ lat_bias,
    float* __restrict__ P, float* __restrict__ latents_zero) {
  __shared__ __align__(16) float As[16][132];
  __shared__ __align__(16) float Bs[16][132];
  const int t = threadIdx.x;
  const int tx = t & 15, ty = t >> 4;
  const int bn = blockIdx.x;  // NDIRS/128
  const int bm = blockIdx.y;  // BATCH/128
  const int lr = t >> 2;        // 0..63
  const int lk = (t & 3) << 2;  // 0,4,8,12

  const float* xA = x + (size_t)(bm * 128 + lr) * DMODEL;
  const float* wB = Wenc + (size_t)(bn * 128 + lr) * DMODEL;

  float acc[8][8];  // current K-panel partial (single sequential FMA chain)
  float tot[8][8];  // combined previous panels
#pragma unroll
  for (int i = 0; i < 8; ++i)
#pragma unroll
    for (int j = 0; j < 8; ++j) { acc[i][j] = 0.f; tot[i][j] = 0.f; }

  for (int tt = 0; tt < DMODEL / 16; ++tt) {
    const int k0 = tt * 16;
    __syncthreads();
    float4 pb = *(const float4*)(pre_bias + k0 + lk);
    float4 a0 = *(const float4*)(xA + k0 + lk);
    float4 a1 = *(const float4*)(xA + (size_t)64 * DMODEL + k0 + lk);
    float4 b0 = *(const float4*)(wB + k0 + lk);
    float4 b1 = *(const float4*)(wB + (size_t)64 * DMODEL + k0 + lk);
    // fp32 subtraction first (reference: xc = fl32(x - pre_bias))
    As[lk + 0][lr] = a0.x - pb.x;
    As[lk + 1][lr] = a0.y - pb.y;
    As[lk + 2][lr] = a0.z - pb.z;
    As[lk + 3][lr] = a0.w - pb.w;
    As[lk + 0][lr + 64] = a1.x - pb.x;
    As[lk + 1][lr + 64] = a1.y - pb.y;
    As[lk + 2][lr + 64] = a1.z - pb.z;
    As[lk + 3][lr + 64] = a1.w - pb.w;
    Bs[lk + 0][lr] = b0.x;  Bs[lk + 1][lr] = b0.y;
    Bs[lk + 2][lr] = b0.z;  Bs[lk + 3][lr] = b0.w;
    Bs[lk + 0][lr + 64] = b1.x;  Bs[lk + 1][lr + 64] = b1.y;
    Bs[lk + 2][lr + 64] = b1.z;  Bs[lk + 3][lr + 64] = b1.w;
    __syncthreads();
#pragma unroll
    for (int k = 0; k < 16; ++k) {
      float a[8], b[8];
      *(float4*)&a[0] = *(const float4*)&As[k][ty * 8];
      *(float4*)&a[4] = *(const float4*)&As[k][ty * 8 + 4];
      *(float4*)&b[0] = *(const float4*)&Bs[k][tx * 8];
      *(float4*)&b[4] = *(const float4*)&Bs[k][tx * 8 + 4];
#pragma unroll
      for (int i = 0; i < 8; ++i)
#pragma unroll
        for (int j = 0; j < 8; ++j) acc[i][j] = fmaf(a[i], b[j], acc[i][j]);
    }
    // K-panel boundary after k=512: fold panel into running total.
    if (tt == FOLD_T0 || tt == FOLD_T1) {
#pragma unroll
      for (int i = 0; i < 8; ++i)
#pragma unroll
        for (int j = 0; j < 8; ++j) { tot[i][j] += acc[i][j]; acc[i][j] = 0.f; }
    }
  }

  const int c0 = bn * 128 + tx * 8;
  float lb8[8];
  *(float4*)&lb8[0] = *(const float4*)(lat_bias + c0);
  *(float4*)&lb8[4] = *(const float4*)(lat_bias + c0 + 4);
  const float4 z4 = make_float4(0.f, 0.f, 0.f, 0.f);
#pragma unroll
  for (int i = 0; i < 8; ++i) {
    const size_t ro = (size_t)(bm * 128 + ty * 8 + i) * NDIRS + c0;
    float o[8];
#pragma unroll
    for (int j = 0; j < 8; ++j) o[j] = (tot[i][j] + acc[i][j]) + lb8[j];
    *(float4*)(P + ro) = *(float4*)&o[0];
    *(float4*)(P + ro + 4) = *(float4*)&o[4];
    *(float4*)(latents_zero + ro) = z4;
    *(float4*)(latents_zero + ro + 4) = z4;
  }
}

// ---- per-row selection on fp32 keys, lower-index tie-break (= lax.top_k) ----
__global__ __launch_bounds__(256) void k_select(
    const float* __restrict__ P, const int* __restrict__ stats,
    float* __restrict__ topk_v, float* __restrict__ topk_i,
    float* __restrict__ auxk_v, float* __restrict__ auxk_i,
    float* __restrict__ latents, float* __restrict__ mval,
    int* __restrict__ midx) {
  __shared__ unsigned hist4[4][2048];
  __shared__ unsigned hist[2048];
  __shared__ unsigned chunk[256];
  __shared__ unsigned candKey[CAND_MAX];
  __shared__ unsigned short candIdx[CAND_MAX];
  __shared__ unsigned sCnt, sT;

  const int t = threadIdx.x;
  const int w = t >> 6;
  const int b = blockIdx.x;
  const float* rp = P + (size_t)b * NDIRS;

  // =================== PASS 1: top-128 over raw row ===================
  for (int i = t; i < 2048; i += 256) {
    hist4[0][i] = 0; hist4[1][i] = 0; hist4[2][i] = 0; hist4[3][i] = 0;
  }
  if (t == 0) { sCnt = 0; sT = 0; }
  __syncthreads();
#pragma unroll
  for (int i = 0; i < 16; ++i) {
    const int e = (i * 256 + t) * 4;
    const float4 v = *(const float4*)(rp + e);
    atomicAdd(&hist4[w][fkey(v.x) >> 21], 1u);
    atomicAdd(&hist4[w][fkey(v.y) >> 21], 1u);
    atomicAdd(&hist4[w][fkey(v.z) >> 21], 1u);
    atomicAdd(&hist4[w][fkey(v.w) >> 21], 1u);
  }
  __syncthreads();
  for (int i = t; i < 2048; i += 256)
    hist[i] = hist4[0][i] + hist4[1][i] + hist4[2][i] + hist4[3][i];
  __syncthreads();
  {
    unsigned cs = 0;
#pragma unroll
    for (int j = 0; j < 8; ++j) cs += hist[t * 8 + j];
    chunk[t] = cs;
    __syncthreads();
    for (int s = 1; s < 256; s <<= 1) {
      unsigned add = (t + s < 256) ? chunk[t + s] : 0;
      __syncthreads();
      chunk[t] += add;
      __syncthreads();
    }
    unsigned suf = (t + 1 < 256) ? chunk[t + 1] : 0;
    for (int j = 7; j >= 0; --j) {
      const unsigned h = hist[t * 8 + j];
      const unsigned ab = suf;
      suf += h;
      if (suf >= MKK && ab < MKK) sT = (unsigned)(t * 8 + j);
    }
  }
  __syncthreads();
  {
    const unsigned T = sT;  // exact for fp32-key ranking
#pragma unroll
    for (int i = 0; i < 16; ++i) {
      const int e = (i * 256 + t) * 4;
      const float4 v = *(const float4*)(rp + e);
      const float hv[4] = {v.x, v.y, v.z, v.w};
#pragma unroll
      for (int c = 0; c < 4; ++c) {
        const unsigned k = fkey(hv[c]);
        if ((k >> 21) >= T) {
          unsigned p = atomicAdd(&sCnt, 1u);
          if (p < CAND_MAX) { candKey[p] = k; candIdx[p] = (unsigned short)(e + c); }
        }
      }
    }
  }
  __syncthreads();
  {
    const unsigned C = sCnt < CAND_MAX ? sCnt : CAND_MAX;
    for (unsigned i = t; i < C; i += 256) {
      const unsigned ki = candKey[i];
      const unsigned ii = candIdx[i];
      unsigned r = 0;
      for (unsigned j = 0; j < C; ++j) {
        const unsigned kj = candKey[j];
        r += (unsigned)((kj > ki) | ((kj == ki) & (candIdx[j] < ii)));
      }
      if (r < MKK) {
        const float vr = fmaxf(rp[ii], 0.f);
        mval[b * MKK + r] = vr;
        midx[b * MKK + r] = (int)ii;
        if (r < KTOP) {
          topk_v[b * KTOP + r] = vr;
          topk_i[b * KTOP + r] = (float)ii;
          latents[(size_t)b * NDIRS + ii] = vr;
        }
      }
    }
  }
  __syncthreads();

  // =================== PASS 2: top-256 over dead-masked row ===================
  for (int i = t; i < 2048; i += 256) {
    hist4[0][i] = 0; hist4[1][i] = 0; hist4[2][i] = 0; hist4[3][i] = 0;
  }
  if (t == 0) { sCnt = 0; sT = 0; }
  __syncthreads();
#pragma unroll
  for (int i = 0; i < 16; ++i) {
    const int e = (i * 256 + t) * 4;
    const float4 v = *(const float4*)(rp + e);
    const int4 s = *(const int4*)(stats + e);
    if (s.x > DEADTHR && v.x > 0.f) atomicAdd(&hist4[w][fkey(v.x) >> 21], 1u);
    if (s.y > DEADTHR && v.y > 0.f) atomicAdd(&hist4[w][fkey(v.y) >> 21], 1u);
    if (s.z > DEADTHR && v.z > 0.f) atomicAdd(&hist4[w][fkey(v.z) >> 21], 1u);
    if (s.w > DEADTHR && v.w > 0.f) atomicAdd(&hist4[w][fkey(v.w) >> 21], 1u);
  }
  __syncthreads();
  for (int i = t; i < 2048; i += 256)
    hist[i] = hist4[0][i] + hist4[1][i] + hist4[2][i] + hist4[3][i];
  __syncthreads();
  {
    unsigned cs = 0;
#pragma unroll
    for (int j = 0; j < 8; ++j) cs += hist[t * 8 + j];
    chunk[t] = cs;
    __syncthreads();
    for (int s = 1; s < 256; s <<= 1) {
      unsigned add = (t + s < 256) ? chunk[t + s] : 0;
      __syncthreads();
      chunk[t] += add;
      __syncthreads();
    }
    unsigned suf = (t + 1 < 256) ? chunk[t + 1] : 0;
    for (int j = 7; j >= 0; --j) {
      const unsigned h = hist[t * 8 + j];
      const unsigned ab = suf;
      suf += h;
      if (suf >= AUXK && ab < AUXK) sT = (unsigned)(t * 8 + j);
    }
  }
  __syncthreads();
  {
    const unsigned T = sT;
#pragma unroll
    for (int i = 0; i < 16; ++i) {
      const int e = (i * 256 + t) * 4;
      const float4 v = *(const float4*)(rp + e);
      const int4 s = *(const int4*)(stats + e);
      const float hv[4] = {v.x, v.y, v.z, v.w};
      const int sv[4] = {s.x, s.y, s.z, s.w};
#pragma unroll
      for (int c = 0; c < 4; ++c) {
        if (sv[c] > DEADTHR && hv[c] > 0.f) {
          const unsigned k = fkey(hv[c]);
          if ((k >> 21) >= T) {
            unsigned p = atomicAdd(&sCnt, 1u);
            if (p < CAND_MAX) { candKey[p] = k; candIdx[p] = (unsigned short)(e + c); }
          }
        }
      }
    }
  }
  __syncthreads();
  {
    const unsigned C = sCnt < CAND_MAX ? sCnt : CAND_MAX;
    for (unsigned i = t; i < C; i += 256) {
      const unsigned ki = candKey[i];
      const unsigned ii = candIdx[i];
      unsigned r = 0;
      for (unsigned j = 0; j < C; ++j) {
        const unsigned kj = candKey[j];
        r += (unsigned)((kj > ki) | ((kj == ki) & (candIdx[j] < ii)));
      }
      if (r < AUXK) {
        auxk_v[b * AUXK + r] = fmaxf(rp[ii], 0.f);
        auxk_i[b * AUXK + r] = (float)ii;
      }
    }
    if (t == 0 && C < AUXK) {  // not reachable with this data distribution
      for (unsigned r = C; r < AUXK; ++r) {
        auxk_v[b * AUXK + r] = 0.f;
        auxk_i[b * AUXK + r] = 0.f;
      }
    }
  }
}

// ---------------- sparse decode: recons (32) and multik_recons (128) ----------------
__global__ __launch_bounds__(256) void k_recons(
    const float* __restrict__ WdT, const float* __restrict__ mval,
    const int* __restrict__ midx, const float* __restrict__ pre_bias,
    float* __restrict__ recons, float* __restrict__ mrecons) {
  __shared__ float sv[MKK];
  __shared__ int si[MKK];
  const int t = threadIdx.x;
  const int b = blockIdx.x;
  if (t < MKK) {
    sv[t] = mval[b * MKK + t];
    si[t] = midx[b * MKK + t];
  }
  __syncthreads();
  const int d = t * 4;
  float4 acc = *(const float4*)(pre_bias + d);
#pragma unroll 4
  for (int i = 0; i < KTOP; ++i) {
    const float v = sv[i];
    const float4 wv = *(const float4*)(WdT + (size_t)si[i] * DMODEL + d);
    acc.x = fmaf(v, wv.x, acc.x);
    acc.y = fmaf(v, wv.y, acc.y);
    acc.z = fmaf(v, wv.z, acc.z);
    acc.w = fmaf(v, wv.w, acc.w);
  }
  *(float4*)(recons + (size_t)b * DMODEL + d) = acc;
#pragma unroll 4
  for (int i = KTOP; i < MKK; ++i) {
    const float v = sv[i];
    const float4 wv = *(const float4*)(WdT + (size_t)si[i] * DMODEL + d);
    acc.x = fmaf(v, wv.x, acc.x);
    acc.y = fmaf(v, wv.y, acc.y);
    acc.z = fmaf(v, wv.z, acc.z);
    acc.w = fmaf(v, wv.w, acc.w);
  }
  *(float4*)(mrecons + (size_t)b * DMODEL + d) = acc;
}

__global__ __launch_bounds__(256) void k_recons_g(
    const float* __restrict__ Wdec, const float* __restrict__ mval,
    const int* __restrict__ midx, const float* __restrict__ pre_bias,
    float* __restrict__ recons, float* __restrict__ mrecons) {
  __shared__ float sv[MKK];
  __shared__ int si[MKK];
  const int t = threadIdx.x;
  const int b = blockIdx.x;
  if (t < MKK) {
    sv[t] = mval[b * MKK + t];
    si[t] = midx[b * MKK + t];
  }
  __syncthreads();
  const int d = t * 4;
  float4 acc = *(const float4*)(pre_bias + d);
#pragma unroll 2
  for (int i = 0; i < MKK; ++i) {
    const float v = sv[i];
    const int j = si[i];
    acc.x = fmaf(v, Wdec[(size_t)(d + 0) * NDIRS + j], acc.x);
    acc.y = fmaf(v, Wdec[(size_t)(d + 1) * NDIRS + j], acc.y);
    acc.z = fmaf(v, Wdec[(size_t)(d + 2) * NDIRS + j], acc.z);
    acc.w = fmaf(v, Wdec[(size_t)(d + 3) * NDIRS + j], acc.w);
    if (i == KTOP - 1) *(float4*)(recons + (size_t)b * DMODEL + d) = acc;
  }
  *(float4*)(mrecons + (size_t)b * DMODEL + d) = acc;
}

extern "C" void kernel_launch(void* const* d_in, const int* in_sizes, int n_in,
                              void* d_out, int out_size, void* d_ws,
                              size_t ws_size, hipStream_t stream) {
  const float* x = (const float*)d_in[0];
  const float* Wenc = (const float*)d_in[1];
  const float* Wdec = (const float*)d_in[2];
  const float* pre_bias = (const float*)d_in[3];
  const float* lat_bias = (const float*)d_in[4];
  const int* stats = (const int*)d_in[5];

  float* out = (float*)d_out;
  float* recons = out;
  float* mrecons = recons + (size_t)BATCH * DMODEL;
  float* topk_v = mrecons + (size_t)BATCH * DMODEL;
  float* topk_i = topk_v + (size_t)BATCH * KTOP;
  float* auxk_v = topk_i + (size_t)BATCH * KTOP;
  float* auxk_i = auxk_v + (size_t)BATCH * AUXK;
  float* P = auxk_i + (size_t)BATCH * AUXK;           // latents_pre_act
  float* latents = P + (size_t)BATCH * NDIRS;

  const size_t mval_b = (size_t)BATCH * MKK * sizeof(float);    // 2 MB
  const size_t wdT_b = (size_t)NDIRS * DMODEL * sizeof(float);  // 64 MB

  float* mval = (float*)d_ws;
  int* midx = (int*)((char*)mval + mval_b);
  float* WdT = (float*)((char*)midx + mval_b);
  const bool useT = ws_size >= 2 * mval_b + wdT_b;

  if (useT) {
    dim3 g(NDIRS / 32, DMODEL / 32);
    k_transpose<<<g, 256, 0, stream>>>(Wdec, WdT);
  }
  {
    dim3 g(NDIRS / 128, BATCH / 128);
    k_gemm_enc<<<g, 256, 0, stream>>>(x, Wenc, pre_bias, lat_bias, P, latents);
  }
  k_select<<<BATCH, 256, 0, stream>>>(P, stats, topk_v, topk_i, auxk_v, auxk_i,
                                      latents, mval, midx);
  if (useT)
    k_recons<<<BATCH, 256, 0, stream>>>(WdT, mval, midx, pre_bias, recons, mrecons);
  else
    k_recons_g<<<BATCH, 256, 0, stream>>>(Wdec, mval, midx, pre_bias, recons, mrecons);
}